// Round 13
// baseline (439.657 us; speedup 1.0000x reference)
//
#include <hip/hip_runtime.h>
#include <hip/hip_bf16.h>

typedef unsigned short u16;
typedef __bf16 bf16x8 __attribute__((ext_vector_type(8)));
typedef float f32x4 __attribute__((ext_vector_type(4)));
typedef unsigned short u16x8 __attribute__((ext_vector_type(8)));
typedef unsigned short u16x4 __attribute__((ext_vector_type(4)));

#define NBATCH 32
#define NTOK   257
#define DMODEL 1024
#define NHEAD  16
#define HDIM   64
#define DMLP   4096
#define MTOK   (NBATCH*NTOK)   /* 8224 */
#define MPAD   8448            /* 33*256 = 66*128 */

__device__ __forceinline__ u16 f2bf(float f){
    __hip_bfloat16 h = __float2bfloat16(f);   // RNE; compiler can pair into v_cvt_pk_bf16_f32
    return *reinterpret_cast<u16*>(&h);
}

__device__ __forceinline__ float bf2f(u16 u){
    return __uint_as_float(((unsigned int)u) << 16);
}

__device__ __forceinline__ f32x4 mfma16(bf16x8 a, bf16x8 b, f32x4 c){
    return __builtin_amdgcn_mfma_f32_16x16x32_bf16(a, b, c, 0, 0, 0);
}

__device__ __forceinline__ void gload16(const void* g, void* l){
    __builtin_amdgcn_global_load_lds(
        (const __attribute__((address_space(1))) unsigned int*)g,
        (__attribute__((address_space(3))) unsigned int*)l, 16, 0, 0);
}

__device__ __forceinline__ float waveSum64(float v){
    #pragma unroll
    for (int d = 1; d < 64; d <<= 1) v += __shfl_xor(v, d);
    return v;
}

// XCD-aware bijective block swizzle (nwg % 8 == 0 for all our GEMM grids)
__device__ __forceinline__ void xcd_swz(int &bx, int &by){
    int gx = gridDim.x;
    int nwg = gx * gridDim.y;
    int bid = blockIdx.y * gx + blockIdx.x;
    int wg = (bid & 7) * (nwg >> 3) + (bid >> 3);
    bx = wg % gx; by = wg / gx;
}

// ------------- fused prep: weight cvt (QSCALE folded) + qkv bias + LN1 ---
__global__ __launch_bounds__(256) void prep_all(
        const float* __restrict__ wq, const float* __restrict__ wk,
        const float* __restrict__ wv, const float* __restrict__ wo,
        const float* __restrict__ f1, const float* __restrict__ f2,
        u16* __restrict__ dst,
        const float* __restrict__ hidden, const float* __restrict__ ln1w,
        const float* __restrict__ ln1b, u16* __restrict__ xln,
        const float* __restrict__ bq, const float* __restrict__ bk,
        const float* __restrict__ bv, float* __restrict__ bqkv){
    int b = blockIdx.x, tid = threadIdx.x;
    if (b < 12288){
        const float* s; int rb; float sc = 1.0f;
        if (b < 1024)      { s = wq; rb = 0;    sc = 0.125f; }
        else if (b < 2048) { s = wk; rb = 1024; }
        else if (b < 3072) { s = wv; rb = 2048; }
        else if (b < 4096) { s = wo; rb = 3072; }
        else if (b < 8192) { s = f1; rb = 4096; }
        else               { s = f2; rb = 8192; }
        size_t li = ((size_t)(b - rb)*256 + tid)*4;
        float4 v = *(const float4*)(s + li);
        u16x4 o = { f2bf(v.x*sc), f2bf(v.y*sc), f2bf(v.z*sc), f2bf(v.w*sc) };
        *(u16x4*)(dst + (size_t)b*1024 + tid*4) = o;
    } else if (b < 12288 + MTOK){
        int row = b - 12288;
        float4 v = ((const float4*)(hidden + (size_t)row*DMODEL))[tid];
        float s = v.x + v.y + v.z + v.w;
        s = waveSum64(s);
        __shared__ float red[8];
        int wv2 = tid >> 6;
        if ((tid & 63) == 0) red[wv2] = s;
        __syncthreads();
        float mean = (red[0]+red[1]+red[2]+red[3]) * (1.0f/1024.0f);
        float dx = v.x-mean, dy = v.y-mean, dz = v.z-mean, dw = v.w-mean;
        float s2 = dx*dx + dy*dy + dz*dz + dw*dw;
        s2 = waveSum64(s2);
        if ((tid & 63) == 0) red[4+wv2] = s2;
        __syncthreads();
        float var = (red[4]+red[5]+red[6]+red[7]) * (1.0f/1024.0f);
        float rs = rsqrtf(var + 1e-5f);
        float4 wl = ((const float4*)ln1w)[tid];
        float4 bl = ((const float4*)ln1b)[tid];
        u16x4 o = { f2bf(dx*rs*wl.x + bl.x), f2bf(dy*rs*wl.y + bl.y),
                    f2bf(dz*rs*wl.z + bl.z), f2bf(dw*rs*wl.w + bl.w) };
        ((u16x4*)(xln + (size_t)row*DMODEL))[tid] = o;
    } else {
        int i = (b - 12288 - MTOK)*256 + tid;   // 0..3071
        float v = (i < 1024) ? bq[i]*0.125f
                             : ((i < 2048) ? bk[i-1024] : bv[i-2048]);
        bqkv[i] = v;
    }
}

// ---------------- LayerNorm (LN2): bf16 in -> bf16 out, 1 block/row ------
__global__ __launch_bounds__(256) void ln_b16(const u16* __restrict__ x,
                                              const float* __restrict__ w,
                                              const float* __restrict__ b,
                                              u16* __restrict__ y){
    int row = blockIdx.x, tid = threadIdx.x;
    u16x4 xv = ((const u16x4*)(x + (size_t)row*DMODEL))[tid];
    float4 v = { bf2f(xv[0]), bf2f(xv[1]), bf2f(xv[2]), bf2f(xv[3]) };
    float s = v.x + v.y + v.z + v.w;
    s = waveSum64(s);
    __shared__ float red[8];
    int wv = tid >> 6;
    if ((tid & 63) == 0) red[wv] = s;
    __syncthreads();
    float mean = (red[0]+red[1]+red[2]+red[3]) * (1.0f/1024.0f);
    float dx = v.x-mean, dy = v.y-mean, dz = v.z-mean, dw = v.w-mean;
    float s2 = dx*dx + dy*dy + dz*dz + dw*dw;
    s2 = waveSum64(s2);
    if ((tid & 63) == 0) red[4+wv] = s2;
    __syncthreads();
    float var = (red[4]+red[5]+red[6]+red[7]) * (1.0f/1024.0f);
    float rs = rsqrtf(var + 1e-5f);
    float4 wl = ((const float4*)w)[tid];
    float4 bl = ((const float4*)b)[tid];
    u16x4 o = { f2bf(dx*rs*wl.x + bl.x), f2bf(dy*rs*wl.y + bl.y),
                f2bf(dz*rs*wl.z + bl.z), f2bf(dw*rs*wl.w + bl.w) };
    ((u16x4*)(y + (size_t)row*DMODEL))[tid] = o;
}

// ---------------- GEMM t256: 256x128 tile, BK=64, 8 waves (4Mx2N) --------
// MFMA operands SWAPPED: lane holds one row (lane&15), 4 consecutive cols
// per acc reg -> u16x4 vectorized epilogue stores.
// EPI: 0 = acc+bias -> bf16 (QKV)   2 = quickgelu(acc+bias) -> bf16 (FC1)
template<int EPI>
__global__ __launch_bounds__(512) void gemm_t256(
        const u16* __restrict__ A, const u16* __restrict__ Wt,
        const float* __restrict__ bias, u16* __restrict__ outb,
        int K, int Nn, int Mvalid){
    __shared__ __align__(16) u16 As[256*64];
    __shared__ __align__(16) u16 Bs[128*64];
    int tid = threadIdx.x, lane = tid & 63, w = tid >> 6;
    int wr = w >> 1, wc = w & 1;        // 4M x 2N
    int bx, by; xcd_swz(bx, by);
    int m0 = by*256, n0 = bx*128;
    int lrow = lane & 15, lk = lane >> 4;
    const f32x4 fz = {0.f,0.f,0.f,0.f};
    f32x4 acc[4][4];
    #pragma unroll
    for (int i = 0; i < 4; i++)
        #pragma unroll
        for (int j = 0; j < 4; j++) acc[i][j] = fz;

    const size_t Ks = (size_t)K;
    int so = w*1024 + lane*16;          // byte offset within an 8KB round
    for (int kt = 0; kt < K; kt += 64){
        #pragma unroll
        for (int i = 0; i < 4; i++){    // A: 32KB = 4 rounds x 8KB
            int o = i*8192 + so;
            int row = o >> 7;
            int gsl = ((o >> 4) & 7) ^ (row & 7);
            gload16(A + (size_t)(m0+row)*Ks + kt + gsl*8, &As[i*4096 + w*512]);
        }
        #pragma unroll
        for (int i = 0; i < 2; i++){    // B: 16KB = 2 rounds x 8KB
            int o = i*8192 + so;
            int row = o >> 7;
            int gsl = ((o >> 4) & 7) ^ (row & 7);
            gload16(Wt + (size_t)(n0+row)*Ks + kt + gsl*8, &Bs[i*4096 + w*512]);
        }
        __syncthreads();
        #pragma unroll
        for (int kk = 0; kk < 2; kk++){
            bf16x8 af[4], bfr[4];
            #pragma unroll
            for (int mi = 0; mi < 4; mi++){
                int row = wr*64 + mi*16 + lrow;        // 0..255
                int sl = (kk*4 + lk) ^ (row & 7);
                af[mi] = *(const bf16x8*)&As[row*64 + sl*8];
            }
            #pragma unroll
            for (int ni = 0; ni < 4; ni++){
                int row = wc*64 + ni*16 + lrow;        // 0..127
                int sl = (kk*4 + lk) ^ (row & 7);
                bfr[ni] = *(const bf16x8*)&Bs[row*64 + sl*8];
            }
            #pragma unroll
            for (int mi = 0; mi < 4; mi++)
                #pragma unroll
                for (int ni = 0; ni < 4; ni++)
                    acc[mi][ni] = mfma16(bfr[ni], af[mi], acc[mi][ni]);
        }
        __syncthreads();
    }
    // epilogue: lane holds row = m..+lrow, cols n..+lk*4+{0..3}
    #pragma unroll
    for (int mi = 0; mi < 4; mi++){
        int row = m0 + wr*64 + mi*16 + lrow;
        if (row < Mvalid){
            size_t rb = (size_t)row*Nn;
            #pragma unroll
            for (int ni = 0; ni < 4; ni++){
                int col0 = n0 + wc*64 + ni*16 + lk*4;
                float4 b4 = *(const float4*)&bias[col0];
                f32x4 a = acc[mi][ni];
                float v0 = a[0]+b4.x, v1 = a[1]+b4.y, v2 = a[2]+b4.z, v3 = a[3]+b4.w;
                if (EPI == 2){
                    v0 = v0 / (1.f + __expf(-1.702f*v0));
                    v1 = v1 / (1.f + __expf(-1.702f*v1));
                    v2 = v2 / (1.f + __expf(-1.702f*v2));
                    v3 = v3 / (1.f + __expf(-1.702f*v3));
                }
                u16x4 o = { f2bf(v0), f2bf(v1), f2bf(v2), f2bf(v3) };
                *(u16x4*)&outb[rb + col0] = o;
            }
        }
    }
}

// ---------------- GEMM n64: narrow-N GEMMs (O-proj, FC2) -----------------
// Swapped-operand layout: lane holds one row, 4 consecutive cols.
// EPI 0 (O-proj): outb = f2bf(addf + acc + bias)  (bf16 h, float4 residual)
// EPI 1 (FC2):    outf = bf2f(addb) + acc + bias  (float4 final stores)
template<int EPI>
__global__ __launch_bounds__(256) void gemm_n64(
        const u16* __restrict__ A, const u16* __restrict__ Wt,
        const float* __restrict__ bias,
        const float* __restrict__ addf, const u16* __restrict__ addb,
        float* __restrict__ outf, u16* __restrict__ outb,
        int K, int Nn, int Mvalid){
    __shared__ __align__(16) u16 As[128*64];
    __shared__ __align__(16) u16 Bs[64*64];
    int tid = threadIdx.x, lane = tid & 63, w = tid >> 6;
    int wr = w >> 1, wc = w & 1;
    int bx, by; xcd_swz(bx, by);
    int m0 = by*128, n0 = bx*64;
    int lrow = lane & 15, lk = lane >> 4;
    const f32x4 fz = {0.f,0.f,0.f,0.f};
    f32x4 acc[4][2];
    #pragma unroll
    for (int i = 0; i < 4; i++){ acc[i][0] = fz; acc[i][1] = fz; }

    const size_t Ks = (size_t)K;
    int so = w*1024 + lane*16;
    for (int kt = 0; kt < K; kt += 64){
        #pragma unroll
        for (int i = 0; i < 4; i++){
            int o = i*4096 + so;
            int row = o >> 7;
            int gsl = ((o >> 4) & 7) ^ (row & 7);
            gload16(A + (size_t)(m0+row)*Ks + kt + gsl*8, &As[i*2048 + w*512]);
        }
        #pragma unroll
        for (int i = 0; i < 2; i++){
            int o = i*4096 + so;
            int row = o >> 7;
            int gsl = ((o >> 4) & 7) ^ (row & 7);
            gload16(Wt + (size_t)(n0+row)*Ks + kt + gsl*8, &Bs[i*2048 + w*512]);
        }
        __syncthreads();
        #pragma unroll
        for (int kk = 0; kk < 2; kk++){
            bf16x8 af[4], bfr[2];
            #pragma unroll
            for (int mi = 0; mi < 4; mi++){
                int row = wr*64 + mi*16 + lrow;
                int sl = (kk*4 + lk) ^ (row & 7);
                af[mi] = *(const bf16x8*)&As[row*64 + sl*8];
            }
            #pragma unroll
            for (int ni = 0; ni < 2; ni++){
                int row = wc*32 + ni*16 + lrow;
                int sl = (kk*4 + lk) ^ (row & 7);
                bfr[ni] = *(const bf16x8*)&Bs[row*64 + sl*8];
            }
            #pragma unroll
            for (int mi = 0; mi < 4; mi++)
                #pragma unroll
                for (int ni = 0; ni < 2; ni++)
                    acc[mi][ni] = mfma16(bfr[ni], af[mi], acc[mi][ni]);
        }
        __syncthreads();
    }
    #pragma unroll
    for (int mi = 0; mi < 4; mi++){
        int row = m0 + wr*64 + mi*16 + lrow;
        if (row < Mvalid){
            size_t rb = (size_t)row*Nn;
            #pragma unroll
            for (int ni = 0; ni < 2; ni++){
                int col0 = n0 + wc*32 + ni*16 + lk*4;
                float4 b4 = *(const float4*)&bias[col0];
                f32x4 a = acc[mi][ni];
                float v0 = a[0]+b4.x, v1 = a[1]+b4.y, v2 = a[2]+b4.z, v3 = a[3]+b4.w;
                size_t idx = rb + col0;
                if (EPI == 0){
                    float4 r4 = *(const float4*)&addf[idx];
                    u16x4 o = { f2bf(r4.x+v0), f2bf(r4.y+v1),
                                f2bf(r4.z+v2), f2bf(r4.w+v3) };
                    *(u16x4*)&outb[idx] = o;
                } else {
                    u16x4 r4 = *(const u16x4*)&addb[idx];
                    float4 o = { bf2f(r4[0])+v0, bf2f(r4[1])+v1,
                                 bf2f(r4[2])+v2, bf2f(r4[3])+v3 };
                    *(float4*)&outf[idx] = o;
                }
            }
        }
    }
}

// ---------------- attention: ONE block per (b,h); 5 serial q-chunks ------
// V^T staged once; K read from global (L2-hot); P in LDS per chunk.
// attn_weights written VECTORIZED from Plds (b128 read -> 2x float4 store),
// issued before PV so store latency hides under MFMAs.
__global__ __launch_bounds__(256) void attn_kernel(
        const u16* __restrict__ qkv, float* __restrict__ preproj,
        u16* __restrict__ ctxb, float* __restrict__ attnw){
    __shared__ __align__(16) u16 Vt[64*296];      // [d][krow], swz rows<256
    __shared__ __align__(16) u16 Plds[9*64*32];   // [kstep][qrow][koff], swz
    int tid = threadIdx.x, lane = tid & 63, w = tid >> 6;
    int bh = blockIdx.x, bq = bh >> 4, hh = bh & 15;
    int lrow = lane & 15, lk = lane >> 4;

    size_t base3 = ((size_t)bq*NTOK)*3072 + hh*HDIM;
    const u16* Kg = qkv + base3 + 1024;
    for (int c = tid; c < 2176; c += 256){
        int row = c >> 3, slot = c & 7;
        u16x8 vv = {0,0,0,0,0,0,0,0};
        if (row < NTOK)
            vv = *(const u16x8*)(qkv + base3 + 2048 + (size_t)row*3072 + slot*8);
        int vr = (row < 256) ? (row ^ (slot << 3)) : row;
        #pragma unroll
        for (int j = 0; j < 8; j++) Vt[(slot*8 + j)*296 + vr] = vv[j];
    }
    for (int i = tid; i < 1536; i += 256){
        int d = i/24, c2 = 272 + (i - d*24);
        Vt[d*296 + c2] = 0;
    }
    for (int idx = tid; idx < 1024; idx += 256){
        int prow = idx >> 4, kk = idx & 15;
        int koff = 16 + kk;
        int slot = ((koff >> 3) ^ (prow >> 2)) & 3;
        Plds[8*2048 + prow*32 + slot*8 + (koff & 7)] = 0;
    }

    // chunk-0 Q fragments
    int tok0 = bq*NTOK + 0 + w*16 + lrow;
    const u16* qp0 = qkv + (size_t)tok0*3072 + hh*HDIM;
    bf16x8 qf0 = *(const bf16x8*)(qp0 + lk*8);
    bf16x8 qf1 = *(const bf16x8*)(qp0 + 32 + lk*8);

    for (int q0 = 0; q0 < 320; q0 += 64){
        // S = q @ k^T, K straight from global (L2-hot)
        f32x4 S[17];
        __builtin_amdgcn_s_setprio(1);
        #pragma unroll
        for (int j = 0; j < 17; j++){
            int kcol = j*16 + lrow;
            const u16* kp = Kg + (size_t)kcol*3072;
            f32x4 a = {0.f,0.f,0.f,0.f};
            bf16x8 b0 = *(const bf16x8*)(kp + lk*8);
            a = mfma16(qf0, b0, a);
            bf16x8 b1 = *(const bf16x8*)(kp + 32 + lk*8);
            S[j] = mfma16(qf1, b1, a);
        }
        __builtin_amdgcn_s_setprio(0);
        #pragma unroll
        for (int r = 0; r < 4; r++){
            float mx = -1e30f;
            #pragma unroll
            for (int j = 0; j < 17; j++){
                bool valid = (j < 16) || (lrow == 0);
                mx = fmaxf(mx, valid ? S[j][r] : -1e30f);
            }
            #pragma unroll
            for (int d = 1; d < 16; d <<= 1) mx = fmaxf(mx, __shfl_xor(mx, d));
            float sum = 0.f;
            #pragma unroll
            for (int j = 0; j < 17; j++){
                bool valid = (j < 16) || (lrow == 0);
                float p = valid ? __expf(S[j][r] - mx) : 0.f;
                S[j][r] = p; sum += p;
            }
            #pragma unroll
            for (int d = 1; d < 16; d <<= 1) sum += __shfl_xor(sum, d);
            float inv = 1.f / sum;
            #pragma unroll
            for (int j = 0; j < 17; j++) S[j][r] *= inv;
        }
        __syncthreads();   // previous chunk's PV + attnw reads of Plds done

        // write P into LDS (bf16) — pure LDS, no global stores here
        #pragma unroll
        for (int r = 0; r < 4; r++){
            int prow = w*16 + lk*4 + r;
            #pragma unroll
            for (int j = 0; j < 17; j++){
                int col = j*16 + lrow;
                int kstep = col >> 5, koff = col & 31;
                int slot = ((koff >> 3) ^ (prow >> 2)) & 3;
                Plds[kstep*2048 + prow*32 + slot*8 + (koff & 7)] = f2bf(S[j][r]);
            }
        }
        __syncthreads();

        // vectorized attn_weights write from Plds (issued before PV)
        {
            int prow = tid >> 2, oct = tid & 3;
            int qrow = q0 + prow;
            if (qrow < NTOK){
                size_t obase = ((size_t)bh*NTOK + qrow)*NTOK;
                int slot = (oct ^ (prow >> 2)) & 3;
                #pragma unroll
                for (int ks = 0; ks < 8; ks++){
                    u16x8 p8 = *(const u16x8*)&Plds[ks*2048 + prow*32 + slot*8];
                    int col = ks*32 + oct*8;
                    float4 lo = { bf2f(p8[0]), bf2f(p8[1]), bf2f(p8[2]), bf2f(p8[3]) };
                    float4 hi = { bf2f(p8[4]), bf2f(p8[5]), bf2f(p8[6]), bf2f(p8[7]) };
                    *(float4*)&attnw[obase + col] = lo;
                    *(float4*)&attnw[obase + col + 4] = hi;
                }
            }
            if (tid < 64){
                int pr = tid, qr = q0 + pr;
                if (qr < NTOK){
                    int sl = (pr >> 2) & 3;   // oct 0 of kstep 8
                    attnw[((size_t)bh*NTOK + qr)*NTOK + 256] =
                        bf2f(Plds[8*2048 + pr*32 + sl*8]);
                }
            }
        }

        // prefetch next chunk's Q fragments (independent of PV below)
        bf16x8 nqf0 = qf0, nqf1 = qf1;
        if (q0 + 64 < 320){
            int tokn = bq*NTOK + q0 + 64 + w*16 + lrow;
            const u16* qpn = qkv + (size_t)tokn*3072 + hh*HDIM;
            nqf0 = *(const bf16x8*)(qpn + lk*8);
            nqf1 = *(const bf16x8*)(qpn + 32 + lk*8);
        }

        // ctx = P @ V  (swapped: reg dim = d, lane&15 = qrow)
        f32x4 C4[4];
        #pragma unroll
        for (int n = 0; n < 4; n++) C4[n] = (f32x4){0.f,0.f,0.f,0.f};
        __builtin_amdgcn_s_setprio(1);
        #pragma unroll
        for (int ks = 0; ks < 9; ks++){
            int prow = w*16 + lrow;
            int slotp = (lk ^ (lrow >> 2)) & 3;
            bf16x8 pf = *(const bf16x8*)&Plds[ks*2048 + prow*32 + slotp*8];
            #pragma unroll
            for (int n = 0; n < 4; n++){
                int d = n*16 + lrow;
                int xv = (d >> 3) & 7;
                int kbase = ks*32 + lk*8;
                int kl = (ks < 8) ? (kbase ^ (xv << 3)) : kbase;
                bf16x8 vf = *(const bf16x8*)&Vt[d*296 + kl];
                C4[n] = mfma16(vf, pf, C4[n]);
            }
        }
        __builtin_amdgcn_s_setprio(0);
        {
            int qrow = q0 + w*16 + lrow;
            if (qrow < NTOK){
                int tok2 = bq*NTOK + qrow;
                size_t ob = (size_t)tok2*DMODEL + hh*HDIM;
                #pragma unroll
                for (int n = 0; n < 4; n++){
                    int d0 = n*16 + lk*4;
                    f32x4 c = C4[n];
                    float4 pv = { c[0], c[1], c[2], c[3] };
                    *(float4*)&preproj[ob + d0] = pv;
                    u16x4 cb = { f2bf(c[0]), f2bf(c[1]), f2bf(c[2]), f2bf(c[3]) };
                    *(u16x4*)&ctxb[ob + d0] = cb;
                }
            }
        }
        qf0 = nqf0; qf1 = nqf1;
    }
}

// ------------------------------- launch ----------------------------------
extern "C" void kernel_launch(void* const* d_in, const int* in_sizes, int n_in,
                              void* d_out, int out_size, void* d_ws, size_t ws_size,
                              hipStream_t stream){
    const float* hidden = (const float*)d_in[0];
    const float* ln1w = (const float*)d_in[1];
    const float* ln1b = (const float*)d_in[2];
    const float* Wq   = (const float*)d_in[3];
    const float* bq   = (const float*)d_in[4];
    const float* Wk   = (const float*)d_in[5];
    const float* bk   = (const float*)d_in[6];
    const float* Wv   = (const float*)d_in[7];
    const float* bv   = (const float*)d_in[8];
    const float* Wo   = (const float*)d_in[9];
    const float* bo   = (const float*)d_in[10];
    const float* ln2w = (const float*)d_in[11];
    const float* ln2b = (const float*)d_in[12];
    const float* fc1w = (const float*)d_in[13];
    const float* fc1b = (const float*)d_in[14];
    const float* fc2w = (const float*)d_in[15];
    const float* fc2b = (const float*)d_in[16];

    float* out0 = (float*)d_out;                       // pre_proj [8224,1024]
    float* out1 = out0 + (size_t)MTOK*DMODEL;          // hidden_out
    float* out2 = out1 + (size_t)MTOK*DMODEL;          // attn_weights

    char* ws = (char*)d_ws;
    // region 0: qkv [MPAD][3072] bf16  UNION  fc1o [MPAD][4096] bf16
    u16* qkvb = (u16*)ws;
    u16* fc1o = (u16*)ws;
    size_t off = (size_t)MPAD*DMLP*2;
    // region 1: xln / ctx [MPAD][1024] bf16 (ctx aliases xln)
    u16* xln  = (u16*)(ws + off);
    u16* ctxb = xln;
    off += (size_t)MPAD*DMODEL*2;
    // region 2: bf16 weights: wqkv[3072][1024], wo, fc1, fc2
    u16* wbase = (u16*)(ws + off);
    u16* wqkv = wbase;
    u16* wob  = wbase + 3*1048576;
    u16* wf1  = wbase + 4*1048576;
    u16* wf2  = wbase + 8*1048576;
    off += (size_t)12*1048576*2;
    // region 3: fused qkv bias + bf16 h
    float* bqkv = (float*)(ws + off);
    off += 16384;
    u16* hb = (u16*)(ws + off);                        // [MPAD][1024] bf16 h

    // fused prep: weight converts + LN1 + qkv bias (one dispatch)
    prep_all<<<12288 + MTOK + 12, 256, 0, stream>>>(
        Wq, Wk, Wv, Wo, fc1w, fc2w, wbase,
        hidden, ln1w, ln1b, xln,
        bq, bk, bv, bqkv);

    // fused QKV: [M,3072] = xln @ wqkv^T + bqkv  (256x128 tiles, 792 blocks)
    gemm_t256<0><<<dim3(24,33), 512, 0, stream>>>(xln, wqkv, bqkv, qkvb, 1024, 3072, MTOK);

    // attention: one block per (b,h) = 512 blocks
    attn_kernel<<<dim3(512,1), 256, 0, stream>>>(qkvb, out0, ctxb, out2);

    // O-proj: h = bf16(hidden + ctx @ Wo^T + bo) -> hb, 1040 blocks
    gemm_n64<0><<<dim3(16,65), 256, 0, stream>>>(ctxb, wob, bo, hidden, nullptr,
                                                 nullptr, hb, 1024, 1024, MTOK);

    // LN2 on bf16 h
    ln_b16<<<MTOK, 256, 0, stream>>>(hb, ln2w, ln2b, xln);

    // FC1: quickgelu(xln @ fc1^T + b) -> fc1o bf16 (256x128 tiles, 1056 blocks)
    gemm_t256<2><<<dim3(32,33), 512, 0, stream>>>(xln, wf1, fc1b, fc1o, 1024, 4096, MTOK);

    // FC2: out1 = bf2f(hb) + fc1o @ fc2^T + b  (fp32 final, float4 stores)
    gemm_n64<1><<<dim3(16,65), 256, 0, stream>>>(fc1o, wf2, fc2b, nullptr, hb,
                                                 out1, nullptr, 4096, 1024, MTOK);
}

// Round 14
// 420.265 us; speedup vs baseline: 1.0461x; 1.0461x over previous
//
#include <hip/hip_runtime.h>

typedef unsigned short u16;
typedef __bf16 bf16x8 __attribute__((ext_vector_type(8)));
typedef float f32x4 __attribute__((ext_vector_type(4)));
typedef unsigned short u16x8 __attribute__((ext_vector_type(8)));
typedef unsigned short u16x4 __attribute__((ext_vector_type(4)));

#define NBATCH 32
#define NTOK   257
#define DMODEL 1024
#define NHEAD  16
#define HDIM   64
#define DMLP   4096
#define MTOK   (NBATCH*NTOK)   /* 8224 */
#define MPAD   8448            /* 33*256 = 66*128 */

__device__ __forceinline__ u16 f2bf(float f){
    unsigned int u = __float_as_uint(f);
    u = u + 0x7fffu + ((u >> 16) & 1u);   // RNE
    return (u16)(u >> 16);
}

__device__ __forceinline__ float bf2f(u16 u){
    return __uint_as_float(((unsigned int)u) << 16);
}

__device__ __forceinline__ f32x4 mfma16(bf16x8 a, bf16x8 b, f32x4 c){
    return __builtin_amdgcn_mfma_f32_16x16x32_bf16(a, b, c, 0, 0, 0);
}

__device__ __forceinline__ void gload16(const void* g, void* l){
    __builtin_amdgcn_global_load_lds(
        (const __attribute__((address_space(1))) unsigned int*)g,
        (__attribute__((address_space(3))) unsigned int*)l, 16, 0, 0);
}

__device__ __forceinline__ float waveSum64(float v){
    #pragma unroll
    for (int d = 1; d < 64; d <<= 1) v += __shfl_xor(v, d);
    return v;
}

// XCD-aware bijective block swizzle (nwg % 8 == 0 for all our GEMM grids)
__device__ __forceinline__ void xcd_swz(int &bx, int &by){
    int gx = gridDim.x;
    int nwg = gx * gridDim.y;
    int bid = blockIdx.y * gx + blockIdx.x;
    int wg = (bid & 7) * (nwg >> 3) + (bid >> 3);
    bx = wg % gx; by = wg / gx;
}

// ------------- fused prep: weight cvt (QSCALE folded) + qkv bias + LN1 ---
__global__ __launch_bounds__(256) void prep_all(
        const float* __restrict__ wq, const float* __restrict__ wk,
        const float* __restrict__ wv, const float* __restrict__ wo,
        const float* __restrict__ f1, const float* __restrict__ f2,
        u16* __restrict__ dst,
        const float* __restrict__ hidden, const float* __restrict__ ln1w,
        const float* __restrict__ ln1b, u16* __restrict__ xln,
        const float* __restrict__ bq, const float* __restrict__ bk,
        const float* __restrict__ bv, float* __restrict__ bqkv){
    int b = blockIdx.x, tid = threadIdx.x;
    if (b < 12288){
        const float* s; int rb; float sc = 1.0f;
        if (b < 1024)      { s = wq; rb = 0;    sc = 0.125f; }
        else if (b < 2048) { s = wk; rb = 1024; }
        else if (b < 3072) { s = wv; rb = 2048; }
        else if (b < 4096) { s = wo; rb = 3072; }
        else if (b < 8192) { s = f1; rb = 4096; }
        else               { s = f2; rb = 8192; }
        size_t li = ((size_t)(b - rb)*256 + tid)*4;
        float4 v = *(const float4*)(s + li);
        u16x4 o = { f2bf(v.x*sc), f2bf(v.y*sc), f2bf(v.z*sc), f2bf(v.w*sc) };
        *(u16x4*)(dst + (size_t)b*1024 + tid*4) = o;
    } else if (b < 12288 + MTOK){
        int row = b - 12288;
        float4 v = ((const float4*)(hidden + (size_t)row*DMODEL))[tid];
        float s = v.x + v.y + v.z + v.w;
        s = waveSum64(s);
        __shared__ float red[8];
        int wv2 = tid >> 6;
        if ((tid & 63) == 0) red[wv2] = s;
        __syncthreads();
        float mean = (red[0]+red[1]+red[2]+red[3]) * (1.0f/1024.0f);
        float dx = v.x-mean, dy = v.y-mean, dz = v.z-mean, dw = v.w-mean;
        float s2 = dx*dx + dy*dy + dz*dz + dw*dw;
        s2 = waveSum64(s2);
        if ((tid & 63) == 0) red[4+wv2] = s2;
        __syncthreads();
        float var = (red[4]+red[5]+red[6]+red[7]) * (1.0f/1024.0f);
        float rs = rsqrtf(var + 1e-5f);
        float4 wl = ((const float4*)ln1w)[tid];
        float4 bl = ((const float4*)ln1b)[tid];
        u16x4 o = { f2bf(dx*rs*wl.x + bl.x), f2bf(dy*rs*wl.y + bl.y),
                    f2bf(dz*rs*wl.z + bl.z), f2bf(dw*rs*wl.w + bl.w) };
        ((u16x4*)(xln + (size_t)row*DMODEL))[tid] = o;
    } else {
        int i = (b - 12288 - MTOK)*256 + tid;   // 0..3071
        float v = (i < 1024) ? bq[i]*0.125f
                             : ((i < 2048) ? bk[i-1024] : bv[i-2048]);
        bqkv[i] = v;
    }
}

// ---------------- LayerNorm (LN2): bf16 in -> bf16 out, 1 block/row ------
__global__ __launch_bounds__(256) void ln_b16(const u16* __restrict__ x,
                                              const float* __restrict__ w,
                                              const float* __restrict__ b,
                                              u16* __restrict__ y){
    int row = blockIdx.x, tid = threadIdx.x;
    u16x4 xv = ((const u16x4*)(x + (size_t)row*DMODEL))[tid];
    float4 v = { bf2f(xv[0]), bf2f(xv[1]), bf2f(xv[2]), bf2f(xv[3]) };
    float s = v.x + v.y + v.z + v.w;
    s = waveSum64(s);
    __shared__ float red[8];
    int wv = tid >> 6;
    if ((tid & 63) == 0) red[wv] = s;
    __syncthreads();
    float mean = (red[0]+red[1]+red[2]+red[3]) * (1.0f/1024.0f);
    float dx = v.x-mean, dy = v.y-mean, dz = v.z-mean, dw = v.w-mean;
    float s2 = dx*dx + dy*dy + dz*dz + dw*dw;
    s2 = waveSum64(s2);
    if ((tid & 63) == 0) red[4+wv] = s2;
    __syncthreads();
    float var = (red[4]+red[5]+red[6]+red[7]) * (1.0f/1024.0f);
    float rs = rsqrtf(var + 1e-5f);
    float4 wl = ((const float4*)w)[tid];
    float4 bl = ((const float4*)b)[tid];
    u16x4 o = { f2bf(dx*rs*wl.x + bl.x), f2bf(dy*rs*wl.y + bl.y),
                f2bf(dz*rs*wl.z + bl.z), f2bf(dw*rs*wl.w + bl.w) };
    ((u16x4*)(y + (size_t)row*DMODEL))[tid] = o;
}

// ---------------- GEMM t256: 256x128 tile, BK=64, 8 waves (4Mx2N) --------
// MFMA operands SWAPPED: lane holds one row (lane&15), 4 consecutive cols
// per acc reg -> u16x4 vectorized epilogue stores.
// EPI: 0 = acc+bias -> bf16 (QKV)   2 = quickgelu(acc+bias) -> bf16 (FC1)
template<int EPI>
__global__ __launch_bounds__(512) void gemm_t256(
        const u16* __restrict__ A, const u16* __restrict__ Wt,
        const float* __restrict__ bias, u16* __restrict__ outb,
        int K, int Nn, int Mvalid){
    __shared__ __align__(16) u16 As[256*64];
    __shared__ __align__(16) u16 Bs[128*64];
    int tid = threadIdx.x, lane = tid & 63, w = tid >> 6;
    int wr = w >> 1, wc = w & 1;        // 4M x 2N
    int bx, by; xcd_swz(bx, by);
    int m0 = by*256, n0 = bx*128;
    int lrow = lane & 15, lk = lane >> 4;
    const f32x4 fz = {0.f,0.f,0.f,0.f};
    f32x4 acc[4][4];
    #pragma unroll
    for (int i = 0; i < 4; i++)
        #pragma unroll
        for (int j = 0; j < 4; j++) acc[i][j] = fz;

    const size_t Ks = (size_t)K;
    int so = w*1024 + lane*16;          // byte offset within an 8KB round
    for (int kt = 0; kt < K; kt += 64){
        #pragma unroll
        for (int i = 0; i < 4; i++){    // A: 32KB = 4 rounds x 8KB
            int o = i*8192 + so;
            int row = o >> 7;
            int gsl = ((o >> 4) & 7) ^ (row & 7);
            gload16(A + (size_t)(m0+row)*Ks + kt + gsl*8, &As[i*4096 + w*512]);
        }
        #pragma unroll
        for (int i = 0; i < 2; i++){    // B: 16KB = 2 rounds x 8KB
            int o = i*8192 + so;
            int row = o >> 7;
            int gsl = ((o >> 4) & 7) ^ (row & 7);
            gload16(Wt + (size_t)(n0+row)*Ks + kt + gsl*8, &Bs[i*4096 + w*512]);
        }
        __syncthreads();
        #pragma unroll
        for (int kk = 0; kk < 2; kk++){
            bf16x8 af[4], bfr[4];
            #pragma unroll
            for (int mi = 0; mi < 4; mi++){
                int row = wr*64 + mi*16 + lrow;        // 0..255
                int sl = (kk*4 + lk) ^ (row & 7);
                af[mi] = *(const bf16x8*)&As[row*64 + sl*8];
            }
            #pragma unroll
            for (int ni = 0; ni < 4; ni++){
                int row = wc*64 + ni*16 + lrow;        // 0..127
                int sl = (kk*4 + lk) ^ (row & 7);
                bfr[ni] = *(const bf16x8*)&Bs[row*64 + sl*8];
            }
            #pragma unroll
            for (int mi = 0; mi < 4; mi++)
                #pragma unroll
                for (int ni = 0; ni < 4; ni++)
                    acc[mi][ni] = mfma16(bfr[ni], af[mi], acc[mi][ni]);
        }
        __syncthreads();
    }
    // epilogue: lane holds row = m..+lrow, cols n..+lk*4+{0..3}
    #pragma unroll
    for (int mi = 0; mi < 4; mi++){
        int row = m0 + wr*64 + mi*16 + lrow;
        if (row < Mvalid){
            size_t rb = (size_t)row*Nn;
            #pragma unroll
            for (int ni = 0; ni < 4; ni++){
                int col0 = n0 + wc*64 + ni*16 + lk*4;
                float4 b4 = *(const float4*)&bias[col0];
                f32x4 a = acc[mi][ni];
                float v0 = a[0]+b4.x, v1 = a[1]+b4.y, v2 = a[2]+b4.z, v3 = a[3]+b4.w;
                if (EPI == 2){
                    v0 = v0 / (1.f + __expf(-1.702f*v0));
                    v1 = v1 / (1.f + __expf(-1.702f*v1));
                    v2 = v2 / (1.f + __expf(-1.702f*v2));
                    v3 = v3 / (1.f + __expf(-1.702f*v3));
                }
                u16x4 o = { f2bf(v0), f2bf(v1), f2bf(v2), f2bf(v3) };
                *(u16x4*)&outb[rb + col0] = o;
            }
        }
    }
}

// ---------------- GEMM n64: 128x64 tile, 4 waves (O-proj) ----------------
// Swapped-operand layout: lane holds one row, 4 consecutive cols.
// EPI 0 (O-proj): outb = f2bf(addf + acc + bias)  (bf16 h, float4 residual)
// EPI 1 (FC2):    outf = bf2f(addb) + acc + bias  (float4 final stores)
template<int EPI>
__global__ __launch_bounds__(256) void gemm_n64(
        const u16* __restrict__ A, const u16* __restrict__ Wt,
        const float* __restrict__ bias,
        const float* __restrict__ addf, const u16* __restrict__ addb,
        float* __restrict__ outf, u16* __restrict__ outb,
        int K, int Nn, int Mvalid){
    __shared__ __align__(16) u16 As[128*64];
    __shared__ __align__(16) u16 Bs[64*64];
    int tid = threadIdx.x, lane = tid & 63, w = tid >> 6;
    int wr = w >> 1, wc = w & 1;
    int bx, by; xcd_swz(bx, by);
    int m0 = by*128, n0 = bx*64;
    int lrow = lane & 15, lk = lane >> 4;
    const f32x4 fz = {0.f,0.f,0.f,0.f};
    f32x4 acc[4][2];
    #pragma unroll
    for (int i = 0; i < 4; i++){ acc[i][0] = fz; acc[i][1] = fz; }

    const size_t Ks = (size_t)K;
    int so = w*1024 + lane*16;
    for (int kt = 0; kt < K; kt += 64){
        #pragma unroll
        for (int i = 0; i < 4; i++){
            int o = i*4096 + so;
            int row = o >> 7;
            int gsl = ((o >> 4) & 7) ^ (row & 7);
            gload16(A + (size_t)(m0+row)*Ks + kt + gsl*8, &As[i*2048 + w*512]);
        }
        #pragma unroll
        for (int i = 0; i < 2; i++){
            int o = i*4096 + so;
            int row = o >> 7;
            int gsl = ((o >> 4) & 7) ^ (row & 7);
            gload16(Wt + (size_t)(n0+row)*Ks + kt + gsl*8, &Bs[i*2048 + w*512]);
        }
        __syncthreads();
        #pragma unroll
        for (int kk = 0; kk < 2; kk++){
            bf16x8 af[4], bfr[2];
            #pragma unroll
            for (int mi = 0; mi < 4; mi++){
                int row = wr*64 + mi*16 + lrow;
                int sl = (kk*4 + lk) ^ (row & 7);
                af[mi] = *(const bf16x8*)&As[row*64 + sl*8];
            }
            #pragma unroll
            for (int ni = 0; ni < 2; ni++){
                int row = wc*32 + ni*16 + lrow;
                int sl = (kk*4 + lk) ^ (row & 7);
                bfr[ni] = *(const bf16x8*)&Bs[row*64 + sl*8];
            }
            #pragma unroll
            for (int mi = 0; mi < 4; mi++)
                #pragma unroll
                for (int ni = 0; ni < 2; ni++)
                    acc[mi][ni] = mfma16(bfr[ni], af[mi], acc[mi][ni]);
        }
        __syncthreads();
    }
    #pragma unroll
    for (int mi = 0; mi < 4; mi++){
        int row = m0 + wr*64 + mi*16 + lrow;
        if (row < Mvalid){
            size_t rb = (size_t)row*Nn;
            #pragma unroll
            for (int ni = 0; ni < 2; ni++){
                int col0 = n0 + wc*32 + ni*16 + lk*4;
                float4 b4 = *(const float4*)&bias[col0];
                f32x4 a = acc[mi][ni];
                float v0 = a[0]+b4.x, v1 = a[1]+b4.y, v2 = a[2]+b4.z, v3 = a[3]+b4.w;
                size_t idx = rb + col0;
                if (EPI == 0){
                    float4 r4 = *(const float4*)&addf[idx];
                    u16x4 o = { f2bf(r4.x+v0), f2bf(r4.y+v1),
                                f2bf(r4.z+v2), f2bf(r4.w+v3) };
                    *(u16x4*)&outb[idx] = o;
                } else {
                    u16x4 r4 = *(const u16x4*)&addb[idx];
                    float4 o = { bf2f(r4[0])+v0, bf2f(r4[1])+v1,
                                 bf2f(r4[2])+v2, bf2f(r4[3])+v3 };
                    *(float4*)&outf[idx] = o;
                }
            }
        }
    }
}

// ---------------- GEMM n64t: 256x64 tile, 8 waves (4Mx2N of 64x32) -------
// Tall variant of n64 for FC2: same wave-tile/schedule/swizzle, 2x per-block
// work -> half the per-block fixed cost; 528 blocks, 40KB LDS (4 blocks/CU).
// EPI 1 only: outf = bf2f(addb) + acc + bias (fp32 final, float4 stores)
__global__ __launch_bounds__(512) void gemm_n64t(
        const u16* __restrict__ A, const u16* __restrict__ Wt,
        const float* __restrict__ bias, const u16* __restrict__ addb,
        float* __restrict__ outf,
        int K, int Nn, int Mvalid){
    __shared__ __align__(16) u16 As[256*64];
    __shared__ __align__(16) u16 Bs[64*64];
    int tid = threadIdx.x, lane = tid & 63, w = tid >> 6;
    int wr = w >> 1, wc = w & 1;        // 4M x 2N
    int bx, by; xcd_swz(bx, by);
    int m0 = by*256, n0 = bx*64;
    int lrow = lane & 15, lk = lane >> 4;
    const f32x4 fz = {0.f,0.f,0.f,0.f};
    f32x4 acc[4][2];
    #pragma unroll
    for (int i = 0; i < 4; i++){ acc[i][0] = fz; acc[i][1] = fz; }

    const size_t Ks = (size_t)K;
    int so = w*1024 + lane*16;          // byte offset within an 8KB round (512t)
    for (int kt = 0; kt < K; kt += 64){
        #pragma unroll
        for (int i = 0; i < 4; i++){    // A: 32KB = 4 rounds x 8KB
            int o = i*8192 + so;
            int row = o >> 7;
            int gsl = ((o >> 4) & 7) ^ (row & 7);
            gload16(A + (size_t)(m0+row)*Ks + kt + gsl*8, &As[i*4096 + w*512]);
        }
        {                               // B: 8KB = 1 round
            int o = so;
            int row = o >> 7;           // 0..63
            int gsl = ((o >> 4) & 7) ^ (row & 7);
            gload16(Wt + (size_t)(n0+row)*Ks + kt + gsl*8, &Bs[w*512]);
        }
        __syncthreads();
        #pragma unroll
        for (int kk = 0; kk < 2; kk++){
            bf16x8 af[4], bfr[2];
            #pragma unroll
            for (int mi = 0; mi < 4; mi++){
                int row = wr*64 + mi*16 + lrow;        // 0..255
                int sl = (kk*4 + lk) ^ (row & 7);
                af[mi] = *(const bf16x8*)&As[row*64 + sl*8];
            }
            #pragma unroll
            for (int ni = 0; ni < 2; ni++){
                int row = wc*32 + ni*16 + lrow;        // 0..63
                int sl = (kk*4 + lk) ^ (row & 7);
                bfr[ni] = *(const bf16x8*)&Bs[row*64 + sl*8];
            }
            #pragma unroll
            for (int mi = 0; mi < 4; mi++)
                #pragma unroll
                for (int ni = 0; ni < 2; ni++)
                    acc[mi][ni] = mfma16(bfr[ni], af[mi], acc[mi][ni]);
        }
        __syncthreads();
    }
    #pragma unroll
    for (int mi = 0; mi < 4; mi++){
        int row = m0 + wr*64 + mi*16 + lrow;
        if (row < Mvalid){
            size_t rb = (size_t)row*Nn;
            #pragma unroll
            for (int ni = 0; ni < 2; ni++){
                int col0 = n0 + wc*32 + ni*16 + lk*4;
                float4 b4 = *(const float4*)&bias[col0];
                f32x4 a = acc[mi][ni];
                size_t idx = rb + col0;
                u16x4 r4 = *(const u16x4*)&addb[idx];
                float4 o = { bf2f(r4[0])+a[0]+b4.x, bf2f(r4[1])+a[1]+b4.y,
                             bf2f(r4[2])+a[2]+b4.z, bf2f(r4[3])+a[3]+b4.w };
                *(float4*)&outf[idx] = o;
            }
        }
    }
}

// ---------------- attention: ONE block per (b,h); 5 serial q-chunks ------
// PV operands swapped: lane holds one qrow (lane&15) x 4 consecutive d
// -> float4 preproj + u16x4 ctxb stores.
__global__ __launch_bounds__(256) void attn_kernel(
        const u16* __restrict__ qkv, float* __restrict__ preproj,
        u16* __restrict__ ctxb, float* __restrict__ attnw){
    __shared__ __align__(16) u16 Vt[64*296];      // [d][krow], swz rows<256
    __shared__ __align__(16) u16 Plds[9*64*32];   // [kstep][qrow][koff], swz
    int tid = threadIdx.x, lane = tid & 63, w = tid >> 6;
    int bh = blockIdx.x, bq = bh >> 4, hh = bh & 15;
    int lrow = lane & 15, lk = lane >> 4;

    size_t base3 = ((size_t)bq*NTOK)*3072 + hh*HDIM;
    const u16* Kg = qkv + base3 + 1024;
    for (int c = tid; c < 2176; c += 256){
        int row = c >> 3, slot = c & 7;
        u16x8 vv = {0,0,0,0,0,0,0,0};
        if (row < NTOK)
            vv = *(const u16x8*)(qkv + base3 + 2048 + (size_t)row*3072 + slot*8);
        int vr = (row < 256) ? (row ^ (slot << 3)) : row;
        #pragma unroll
        for (int j = 0; j < 8; j++) Vt[(slot*8 + j)*296 + vr] = vv[j];
    }
    for (int i = tid; i < 1536; i += 256){
        int d = i/24, c2 = 272 + (i - d*24);
        Vt[d*296 + c2] = 0;
    }
    for (int idx = tid; idx < 1024; idx += 256){
        int prow = idx >> 4, kk = idx & 15;
        int koff = 16 + kk;
        int slot = ((koff >> 3) ^ (prow >> 2)) & 3;
        Plds[8*2048 + prow*32 + slot*8 + (koff & 7)] = 0;
    }

    // chunk-0 Q fragments
    int tok0 = bq*NTOK + 0 + w*16 + lrow;
    const u16* qp0 = qkv + (size_t)tok0*3072 + hh*HDIM;
    bf16x8 qf0 = *(const bf16x8*)(qp0 + lk*8);
    bf16x8 qf1 = *(const bf16x8*)(qp0 + 32 + lk*8);

    for (int q0 = 0; q0 < 320; q0 += 64){
        // S = q @ k^T, K straight from global (L2-hot)
        f32x4 S[17];
        __builtin_amdgcn_s_setprio(1);
        #pragma unroll
        for (int j = 0; j < 17; j++){
            int kcol = j*16 + lrow;
            const u16* kp = Kg + (size_t)kcol*3072;
            f32x4 a = {0.f,0.f,0.f,0.f};
            bf16x8 b0 = *(const bf16x8*)(kp + lk*8);
            a = mfma16(qf0, b0, a);
            bf16x8 b1 = *(const bf16x8*)(kp + 32 + lk*8);
            S[j] = mfma16(qf1, b1, a);
        }
        __builtin_amdgcn_s_setprio(0);
        #pragma unroll
        for (int r = 0; r < 4; r++){
            float mx = -1e30f;
            #pragma unroll
            for (int j = 0; j < 17; j++){
                bool valid = (j < 16) || (lrow == 0);
                mx = fmaxf(mx, valid ? S[j][r] : -1e30f);
            }
            #pragma unroll
            for (int d = 1; d < 16; d <<= 1) mx = fmaxf(mx, __shfl_xor(mx, d));
            float sum = 0.f;
            #pragma unroll
            for (int j = 0; j < 17; j++){
                bool valid = (j < 16) || (lrow == 0);
                float p = valid ? __expf(S[j][r] - mx) : 0.f;
                S[j][r] = p; sum += p;
            }
            #pragma unroll
            for (int d = 1; d < 16; d <<= 1) sum += __shfl_xor(sum, d);
            float inv = 1.f / sum;
            #pragma unroll
            for (int j = 0; j < 17; j++) S[j][r] *= inv;
        }
        __syncthreads();   // previous chunk's PV reads of Plds are done

        #pragma unroll
        for (int r = 0; r < 4; r++){
            int rw = lk*4 + r;
            int qrow = q0 + w*16 + rw;
            bool rowok = qrow < NTOK;
            size_t obase = ((size_t)bh*NTOK + qrow)*NTOK;
            int prow = w*16 + rw;
            #pragma unroll
            for (int j = 0; j < 17; j++){
                int col = j*16 + lrow;
                float p = S[j][r];
                if (rowok && col < NTOK) attnw[obase + col] = p;
                int kstep = col >> 5, koff = col & 31;
                int slot = ((koff >> 3) ^ (prow >> 2)) & 3;
                Plds[kstep*2048 + prow*32 + slot*8 + (koff & 7)] = f2bf(p);
            }
        }
        __syncthreads();

        // prefetch next chunk's Q fragments (independent of PV below)
        bf16x8 nqf0 = qf0, nqf1 = qf1;
        if (q0 + 64 < 320){
            int tokn = bq*NTOK + q0 + 64 + w*16 + lrow;
            const u16* qpn = qkv + (size_t)tokn*3072 + hh*HDIM;
            nqf0 = *(const bf16x8*)(qpn + lk*8);
            nqf1 = *(const bf16x8*)(qpn + 32 + lk*8);
        }

        // ctx = P @ V  (swapped: reg dim = d, lane&15 = qrow)
        f32x4 C4[4];
        #pragma unroll
        for (int n = 0; n < 4; n++) C4[n] = (f32x4){0.f,0.f,0.f,0.f};
        __builtin_amdgcn_s_setprio(1);
        #pragma unroll
        for (int ks = 0; ks < 9; ks++){
            int prow = w*16 + lrow;
            int slotp = (lk ^ (lrow >> 2)) & 3;
            bf16x8 pf = *(const bf16x8*)&Plds[ks*2048 + prow*32 + slotp*8];
            #pragma unroll
            for (int n = 0; n < 4; n++){
                int d = n*16 + lrow;
                int xv = (d >> 3) & 7;
                int kbase = ks*32 + lk*8;
                int kl = (ks < 8) ? (kbase ^ (xv << 3)) : kbase;
                bf16x8 vf = *(const bf16x8*)&Vt[d*296 + kl];
                C4[n] = mfma16(vf, pf, C4[n]);
            }
        }
        __builtin_amdgcn_s_setprio(0);
        {
            int qrow = q0 + w*16 + lrow;
            if (qrow < NTOK){
                int tok2 = bq*NTOK + qrow;
                size_t ob = (size_t)tok2*DMODEL + hh*HDIM;
                #pragma unroll
                for (int n = 0; n < 4; n++){
                    int d0 = n*16 + lk*4;
                    f32x4 c = C4[n];
                    float4 pv = { c[0], c[1], c[2], c[3] };
                    *(float4*)&preproj[ob + d0] = pv;
                    u16x4 cb = { f2bf(c[0]), f2bf(c[1]), f2bf(c[2]), f2bf(c[3]) };
                    *(u16x4*)&ctxb[ob + d0] = cb;
                }
            }
        }
        qf0 = nqf0; qf1 = nqf1;
    }
}

// ------------------------------- launch ----------------------------------
extern "C" void kernel_launch(void* const* d_in, const int* in_sizes, int n_in,
                              void* d_out, int out_size, void* d_ws, size_t ws_size,
                              hipStream_t stream){
    const float* hidden = (const float*)d_in[0];
    const float* ln1w = (const float*)d_in[1];
    const float* ln1b = (const float*)d_in[2];
    const float* Wq   = (const float*)d_in[3];
    const float* bq   = (const float*)d_in[4];
    const float* Wk   = (const float*)d_in[5];
    const float* bk   = (const float*)d_in[6];
    const float* Wv   = (const float*)d_in[7];
    const float* bv   = (const float*)d_in[8];
    const float* Wo   = (const float*)d_in[9];
    const float* bo   = (const float*)d_in[10];
    const float* ln2w = (const float*)d_in[11];
    const float* ln2b = (const float*)d_in[12];
    const float* fc1w = (const float*)d_in[13];
    const float* fc1b = (const float*)d_in[14];
    const float* fc2w = (const float*)d_in[15];
    const float* fc2b = (const float*)d_in[16];

    float* out0 = (float*)d_out;                       // pre_proj [8224,1024]
    float* out1 = out0 + (size_t)MTOK*DMODEL;          // hidden_out
    float* out2 = out1 + (size_t)MTOK*DMODEL;          // attn_weights

    char* ws = (char*)d_ws;
    // region 0: qkv [MPAD][3072] bf16  UNION  fc1o [MPAD][4096] bf16
    u16* qkvb = (u16*)ws;
    u16* fc1o = (u16*)ws;
    size_t off = (size_t)MPAD*DMLP*2;
    // region 1: xln / ctx [MPAD][1024] bf16 (ctx aliases xln)
    u16* xln  = (u16*)(ws + off);
    u16* ctxb = xln;
    off += (size_t)MPAD*DMODEL*2;
    // region 2: bf16 weights: wqkv[3072][1024], wo, fc1, fc2
    u16* wbase = (u16*)(ws + off);
    u16* wqkv = wbase;
    u16* wob  = wbase + 3*1048576;
    u16* wf1  = wbase + 4*1048576;
    u16* wf2  = wbase + 8*1048576;
    off += (size_t)12*1048576*2;
    // region 3: fused qkv bias + bf16 h
    float* bqkv = (float*)(ws + off);
    off += 16384;
    u16* hb = (u16*)(ws + off);                        // [MPAD][1024] bf16 h

    // fused prep: weight converts + LN1 + qkv bias (one dispatch)
    prep_all<<<12288 + MTOK + 12, 256, 0, stream>>>(
        Wq, Wk, Wv, Wo, fc1w, fc2w, wbase,
        hidden, ln1w, ln1b, xln,
        bq, bk, bv, bqkv);

    // fused QKV: [M,3072] = xln @ wqkv^T + bqkv  (256x128 tiles, 792 blocks)
    gemm_t256<0><<<dim3(24,33), 512, 0, stream>>>(xln, wqkv, bqkv, qkvb, 1024, 3072, MTOK);

    // attention: one block per (b,h) = 512 blocks
    attn_kernel<<<dim3(512,1), 256, 0, stream>>>(qkvb, out0, ctxb, out2);

    // O-proj: h = bf16(hidden + ctx @ Wo^T + bo) -> hb, 1040 blocks (control)
    gemm_n64<0><<<dim3(16,65), 256, 0, stream>>>(ctxb, wob, bo, hidden, nullptr,
                                                 nullptr, hb, 1024, 1024, MTOK);

    // LN2 on bf16 h
    ln_b16<<<MTOK, 256, 0, stream>>>(hb, ln2w, ln2b, xln);

    // FC1: quickgelu(xln @ fc1^T + b) -> fc1o bf16 (256x128 tiles, 1056 blocks)
    gemm_t256<2><<<dim3(32,33), 512, 0, stream>>>(xln, wf1, fc1b, fc1o, 1024, 4096, MTOK);

    // FC2 [experiment]: tall 256x64 tiles, 528 blocks
    gemm_n64t<<<dim3(16,33), 512, 0, stream>>>(fc1o, wf2, fc2b, hb, out1, 4096, 1024, MTOK);
}